// Round 1
// baseline (1205.544 us; speedup 1.0000x reference)
//
#include <hip/hip_runtime.h>
#include <hip/hip_bf16.h>

#define NPTS 4096
#define FIN  64
#define FOUT 128
#define KNB  16
#define BATCH 8
#define BN_EPS 1e-5f
#define FINF 1e30f

// ---------------- ws layout (bytes) ----------------
#define OFF_SQ     (0)
#define OFF_IDX    (OFF_SQ + BATCH*NPTS*4)              // B*N ints->floats? sq floats
#define OFF_UBAR   (OFF_IDX + BATCH*NPTS*KNB*4)
#define OFF_VT     (OFF_UBAR + BATCH*NPTS*FOUT*4)
#define OFF_GSUM   (OFF_VT + BATCH*NPTS*FOUT*4)
#define OFF_GSUMSQ (OFF_GSUM + FOUT*4)
#define OFF_AC     (OFF_GSUMSQ + FOUT*4)
// total ~= 35.8 MB

// ---------------- sq[b,n] = sum_f x^2 ----------------
__global__ __launch_bounds__(256) void sq_kernel(const float* __restrict__ x, float* __restrict__ sq){
  int bn = blockIdx.x*256 + threadIdx.x;
  int b = bn >> 12, n = bn & (NPTS-1);
  const float* xp = x + (size_t)b*FIN*NPTS + n;
  float s = 0.f;
  #pragma unroll
  for (int f=0; f<FIN; ++f){ float v = xp[(size_t)f*NPTS]; s = fmaf(v,v,s); }
  sq[bn] = s;
}

// ---------------- Ubar = (W1-W2)x + b ; Vt = W2 x  (point-major [bn][o]) ----------------
__global__ __launch_bounds__(256) void uv_kernel(const float* __restrict__ x, const float* __restrict__ W,
                                                 const float* __restrict__ bias,
                                                 float* __restrict__ ubar, float* __restrict__ vt){
  int bn = blockIdx.x*256 + threadIdx.x;
  int b = bn >> 12, n = bn & (NPTS-1);
  const float* xp = x + (size_t)b*FIN*NPTS + n;
  float xc[FIN];
  #pragma unroll
  for (int f=0; f<FIN; ++f) xc[f] = xp[(size_t)f*NPTS];   // coalesced across threads per f
  float* up = ubar + (size_t)bn*FOUT;
  float* vp = vt   + (size_t)bn*FOUT;
  for (int o=0; o<FOUT; ++o){                              // o uniform -> W via scalar loads
    const float* wr = W + o*2*FIN;
    float a1=0.f, a2=0.f;
    #pragma unroll
    for (int f=0; f<FIN; ++f){ a1 = fmaf(wr[f], xc[f], a1); a2 = fmaf(wr[FIN+f], xc[f], a2); }
    up[o] = a1 - a2 + bias[o];
    vp[o] = a2;
  }
}

// ---------------- fused distances + top-16 ----------------
// block: 256 thr = 4 waves; 64 rows/block (16 rows/wave); chunk = 64 candidates.
// lane = (cl=l&15 -> 4 cands, rl=l>>4 -> 4 rows): 4x4 register tile, K=64 via LDS.
// xt is XOR-swizzled: word c*64 + (f ^ (c&60)) holds x[f][c0+c]  -> b128 reads, ~2-way banks.
__global__ __launch_bounds__(256) void knn_kernel(const float* __restrict__ x, const float* __restrict__ sq,
                                                  int* __restrict__ idxout){
  __shared__ float xt[64*64];
  __shared__ float rowf[64*72];   // [row][f], pad 72 (16B-aligned rows)
  __shared__ float rowsq[64];
  __shared__ float dtile[64*68];  // [row][cand], pad 68 -> 2-way on strided read
  const int t = threadIdx.x;
  const int w = t >> 6;
  const int l = t & 63;
  const int b  = blockIdx.x;          // grid.x = batch -> XCD ~ batch (L2 locality)
  const int n0 = blockIdx.y * 64;
  const float* xb = x + (size_t)b*FIN*NPTS;

  for (int j=t; j<4096; j+=256){ int row = j & 63, f = j >> 6; rowf[row*72+f] = xb[(size_t)f*NPTS + n0 + row]; }
  if (t < 64) rowsq[t] = sq[b*NPTS + n0 + t];
  __syncthreads();

  const int cl = l & 15;
  const int rl = l >> 4;
  float rsq[4]; int nself[4];
  #pragma unroll
  for (int jr=0;jr<4;++jr){ int r = w*16 + rl*4 + jr; rsq[jr] = rowsq[r]; nself[jr] = n0 + r; }

  float val[16]; int idx[16];
  #pragma unroll
  for (int q=0;q<16;++q){ val[q] = FINF; idx[q] = 0; }
  const int selrow = w*16 + (l>>2);
  const int selc   = l & 3;

  for (int c0=0; c0<NPTS; c0+=64){
    __syncthreads();                           // xt free to overwrite
    #pragma unroll
    for (int it=0; it<4; ++it){                // stage 64f x 64c, pre-swizzled
      int i4 = it*256 + t;
      int f  = i4 >> 4;
      int c4 = (i4 & 15) << 2;
      float4 v = *(const float4*)(xb + (size_t)f*NPTS + c0 + c4);
      int fp = f ^ c4;                         // (c&60)==c4 for all 4 elems
      xt[(c4+0)*64 + fp] = v.x;
      xt[(c4+1)*64 + fp] = v.y;
      xt[(c4+2)*64 + fp] = v.z;
      xt[(c4+3)*64 + fp] = v.w;
    }
    float csq[4];
    #pragma unroll
    for (int jc=0;jc<4;++jc) csq[jc] = sq[b*NPTS + c0 + cl*4 + jc];
    __syncthreads();                           // xt ready

    float acc[4][4];
    #pragma unroll
    for (int jc=0;jc<4;++jc){
      #pragma unroll
      for (int jr=0;jr<4;++jr) acc[jc][jr]=0.f;
    }
    #pragma unroll
    for (int i=0;i<16;++i){                    // logical f4 = 4i; physical = 4(i^cl)
      int fp = ((i ^ cl) << 2);
      float4 xv[4], rf[4];
      #pragma unroll
      for (int jc=0;jc<4;++jc) xv[jc] = *(const float4*)&xt[(cl*4+jc)*64 + fp];
      #pragma unroll
      for (int jr=0;jr<4;++jr) rf[jr] = *(const float4*)&rowf[(w*16+rl*4+jr)*72 + i*4];
      #pragma unroll
      for (int jc=0;jc<4;++jc){
        #pragma unroll
        for (int jr=0;jr<4;++jr){
          acc[jc][jr] = fmaf(xv[jc].x, rf[jr].x, acc[jc][jr]);
          acc[jc][jr] = fmaf(xv[jc].y, rf[jr].y, acc[jc][jr]);
          acc[jc][jr] = fmaf(xv[jc].z, rf[jr].z, acc[jc][jr]);
          acc[jc][jr] = fmaf(xv[jc].w, rf[jr].w, acc[jc][jr]);
        }
      }
    }
    #pragma unroll
    for (int jc=0;jc<4;++jc){
      int c = c0 + cl*4 + jc;
      #pragma unroll
      for (int jr=0;jr<4;++jr){
        float d = fmaf(-2.f, acc[jc][jr], rsq[jr] + csq[jc]);
        if (c == nself[jr]) d = FINF;          // exclude self (ref drops rank-0 = self)
        dtile[(w*16 + rl*4 + jr)*68 + cl*4 + jc] = d;
      }
    }
    // selection: lane scans 16 cands of its row (same-wave LDS, no barrier)
    #pragma unroll
    for (int j=0;j<16;++j){
      float d = dtile[selrow*68 + selc + j*4];
      if (d < val[15]){
        int m = c0 + selc + j*4;
        val[15] = d; idx[15] = m;
        #pragma unroll
        for (int q=15;q>0;--q){
          bool s_ = val[q] < val[q-1];
          float tv = val[q], tu = val[q-1];
          val[q]   = s_ ? tu : tv;
          val[q-1] = s_ ? tv : tu;
          int iv = idx[q], iu = idx[q-1];
          idx[q]   = s_ ? iu : iv;
          idx[q-1] = s_ ? iv : iu;
        }
      }
    }
  }

  // merge 4 sorted lists per row -> global top-16 (order irrelevant: max over k later)
  int myidx[4];
  #pragma unroll
  for (int round=0; round<16; ++round){
    float v = val[0]; int ii = idx[0]; int src = selc;
    #pragma unroll
    for (int mm=1; mm<4; mm<<=1){
      float ov = __shfl_xor(v, mm);
      int   oi = __shfl_xor(ii, mm);
      int   os = __shfl_xor(src, mm);
      bool take = (ov < v) || (ov == v && os < src);
      v = take ? ov : v; ii = take ? oi : ii; src = take ? os : src;
    }
    if (selc == src){
      #pragma unroll
      for (int q=0;q<15;++q){ val[q]=val[q+1]; idx[q]=idx[q+1]; }
      val[15] = FINF;
    }
    if ((round & 3) == selc) myidx[round>>2] = ii;
  }
  {
    int row = n0 + selrow;
    int* op = idxout + ((size_t)(b*NPTS + row))*KNB;
    #pragma unroll
    for (int q=0;q<4;++q) op[q*4 + selc] = myidx[q];
  }
}

// ---------------- gather V at neighbors: sel=Ubar+(g>=0?max:min), channel stats ----------------
__global__ __launch_bounds__(256) void gather_kernel(const float* __restrict__ vt, const float* __restrict__ ubar,
                                                     const int* __restrict__ idxnb, const float* __restrict__ gamma,
                                                     float* __restrict__ outsel, float* __restrict__ gsum,
                                                     float* __restrict__ gsumsq){
  __shared__ float cmb[4*FOUT];
  const int t = threadIdx.x;
  const int o = t & 127;
  const int g = t >> 7;                 // two halves of the 16 neighbors
  const int b = blockIdx.x;             // XCD ~ batch
  const int n_base = blockIdx.y*32;
  const float gam = gamma[o];
  float bs = 0.f, bsq = 0.f;
  for (int p=0; p<32; ++p){
    int n  = n_base + p;
    int bn = b*NPTS + n;
    const int* ip = idxnb + (size_t)bn*KNB + g*8;   // wave-uniform -> s_load
    float mx = -FINF, mn = FINF, s1 = 0.f, s2 = 0.f;
    #pragma unroll
    for (int kk=0; kk<8; ++kk){
      int m = ip[kk];
      float v = vt[((size_t)(b*NPTS + m))*FOUT + o];  // 512B coalesced per neighbor
      mx = fmaxf(mx, v); mn = fminf(mn, v); s1 += v; s2 = fmaf(v, v, s2);
    }
    if (g == 1){ cmb[o] = mx; cmb[FOUT+o] = mn; cmb[2*FOUT+o] = s1; cmb[3*FOUT+o] = s2; }
    __syncthreads();
    if (g == 0){
      mx = fmaxf(mx, cmb[o]); mn = fminf(mn, cmb[FOUT+o]); s1 += cmb[2*FOUT+o]; s2 += cmb[3*FOUT+o];
      float c = ubar[(size_t)bn*FOUT + o];
      // write pre-BN selected extreme directly in FINAL [b][o][n] layout (L2 merges partial lines)
      outsel[((size_t)b*FOUT + o)*NPTS + n] = c + (gam >= 0.f ? mx : mn);
      bs  += fmaf(16.f, c, s1);                       // sum_k y = 16c + S1
      bsq += fmaf(16.f*c, c, fmaf(2.f*c, s1, s2));    // sum_k y^2 = 16c^2 + 2c S1 + S2
    }
    __syncthreads();
  }
  if (g == 0){ atomicAdd(&gsum[o], bs); atomicAdd(&gsumsq[o], bsq); }
}

// ---------------- BN stats -> per-channel affine a,c ----------------
__global__ void stats_kernel(const float* __restrict__ gsum, const float* __restrict__ gsumsq,
                             const float* __restrict__ gamma, const float* __restrict__ beta,
                             float* __restrict__ ac){
  int o = threadIdx.x;
  const float invM = 1.f / (float)(BATCH*NPTS*KNB);
  float mean = gsum[o] * invM;
  float var  = gsumsq[o] * invM - mean*mean;
  float r = rsqrtf(var + BN_EPS);
  float a = gamma[o] * r;
  ac[o] = a;
  ac[FOUT+o] = beta[o] - mean * a;
}

// ---------------- in-place relu(a*y+c) on d_out ----------------
__global__ __launch_bounds__(256) void apply_kernel(float* __restrict__ out, const float* __restrict__ ac){
  int i4 = blockIdx.x*256 + threadIdx.x;
  int o = (i4 >> 10) & 127;          // 1024 float4 per (b,o) row; wave-uniform
  float a = ac[o], c = ac[FOUT+o];
  float4* p = (float4*)out;
  float4 v = p[i4];
  v.x = fmaxf(fmaf(a, v.x, c), 0.f);
  v.y = fmaxf(fmaf(a, v.y, c), 0.f);
  v.z = fmaxf(fmaf(a, v.z, c), 0.f);
  v.w = fmaxf(fmaf(a, v.w, c), 0.f);
  p[i4] = v;
}

extern "C" void kernel_launch(void* const* d_in, const int* in_sizes, int n_in,
                              void* d_out, int out_size, void* d_ws, size_t ws_size,
                              hipStream_t stream){
  const float* x     = (const float*)d_in[0];
  const float* W     = (const float*)d_in[1];
  const float* bias  = (const float*)d_in[2];
  const float* gamma = (const float*)d_in[3];
  const float* beta  = (const float*)d_in[4];
  char* ws = (char*)d_ws;
  float* sq     = (float*)(ws + OFF_SQ);
  int*   idxnb  = (int*)(ws + OFF_IDX);
  float* ubar   = (float*)(ws + OFF_UBAR);
  float* vt     = (float*)(ws + OFF_VT);
  float* gsum   = (float*)(ws + OFF_GSUM);
  float* gsumsq = (float*)(ws + OFF_GSUMSQ);
  float* ac     = (float*)(ws + OFF_AC);
  float* out    = (float*)d_out;

  hipMemsetAsync(ws + OFF_GSUM, 0, 2*FOUT*4, stream);
  sq_kernel   <<<BATCH*NPTS/256, 256, 0, stream>>>(x, sq);
  uv_kernel   <<<BATCH*NPTS/256, 256, 0, stream>>>(x, W, bias, ubar, vt);
  knn_kernel  <<<dim3(BATCH, NPTS/64), 256, 0, stream>>>(x, sq, idxnb);
  gather_kernel<<<dim3(BATCH, NPTS/32), 256, 0, stream>>>(vt, ubar, idxnb, gamma, out, gsum, gsumsq);
  stats_kernel<<<1, FOUT, 0, stream>>>(gsum, gsumsq, gamma, beta, ac);
  apply_kernel<<<BATCH*FOUT*NPTS/1024, 256, 0, stream>>>(out, ac);
}

// Round 2
// 704.833 us; speedup vs baseline: 1.7104x; 1.7104x over previous
//
#include <hip/hip_runtime.h>
#include <hip/hip_bf16.h>

#define NPTS 4096
#define FIN  64
#define FOUT 128
#define KNB  16
#define BATCH 8
#define BN_EPS 1e-5f
#define FINF 1e30f

// ---------------- ws layout (bytes) ----------------
#define OFF_SQ     (0)
#define OFF_IDX    (OFF_SQ + BATCH*NPTS*4)
#define OFF_PAIRS  (OFF_IDX + BATCH*NPTS*KNB*4)
#define OFF_UBAR   (OFF_PAIRS + BATCH*NPTS*32*8)
#define OFF_VT     (OFF_UBAR + BATCH*NPTS*FOUT*4)
#define OFF_GSUM   (OFF_VT + BATCH*NPTS*FOUT*4)
#define OFF_GSUMSQ (OFF_GSUM + FOUT*4)
#define OFF_AC     (OFF_GSUMSQ + FOUT*4)
// total ~= 44.2 MB

// ---------------- sq[b,n] = sum_f x^2 ----------------
__global__ __launch_bounds__(256) void sq_kernel(const float* __restrict__ x, float* __restrict__ sq){
  int bn = blockIdx.x*256 + threadIdx.x;
  int b = bn >> 12, n = bn & (NPTS-1);
  const float* xp = x + (size_t)b*FIN*NPTS + n;
  float s = 0.f;
  #pragma unroll
  for (int f=0; f<FIN; ++f){ float v = xp[(size_t)f*NPTS]; s = fmaf(v,v,s); }
  sq[bn] = s;
}

// ---------------- Ubar = (W1-W2)x + b ; Vt = W2 x  (point-major [bn][o]) ----------------
// block 256 = 4 waves; block covers 64 points, wave w computes o in [w*32, w*32+32)
__global__ __launch_bounds__(256) void uv_kernel(const float* __restrict__ x, const float* __restrict__ W,
                                                 const float* __restrict__ bias,
                                                 float* __restrict__ ubar, float* __restrict__ vt){
  const int t = threadIdx.x, l = t & 63;
  const int w = __builtin_amdgcn_readfirstlane(t >> 6);   // wave-uniform -> W via s_load
  const int bid = blockIdx.x;
  const int b = bid & 7, grp = bid >> 3;                  // consecutive blocks round-robin XCDs -> batch b on XCD b
  const int n = grp*64 + l;
  const float* xp = x + (size_t)b*FIN*NPTS + n;
  float xc[FIN];
  #pragma unroll
  for (int f=0; f<FIN; ++f) xc[f] = xp[(size_t)f*NPTS];   // coalesced per f
  const size_t bn = (size_t)b*NPTS + n;
  float* up = ubar + bn*FOUT;
  float* vp = vt   + bn*FOUT;
  for (int o = w*32; o < w*32+32; ++o){
    const float* wr = W + o*2*FIN;
    float a1=0.f, a2=0.f;
    #pragma unroll
    for (int f=0; f<FIN; ++f){ a1 = fmaf(wr[f], xc[f], a1); a2 = fmaf(wr[FIN+f], xc[f], a2); }
    up[o] = a1 - a2 + bias[o];
    vp[o] = a2;
  }
}

// ---------------- fused distances + top-16 (half candidate range per block) ----------------
// 256 thr = 4 waves; 64 rows/block; candidate range [z*2048, z*2048+2048), chunk = 64.
// compute lane: (cl=l&15 -> 4 cands, rl=l>>4 -> 4 rows) 4x4 register tile, K=64 via LDS.
// selection lane: row = w*16 + l>>2, owns cands == selc (mod 4).
__global__ __launch_bounds__(256,3) void knn_kernel(const float* __restrict__ x, const float* __restrict__ sq,
                                                    float2* __restrict__ pairs){
  __shared__ float xt[64*64];
  __shared__ float rowf[64*68];   // stride 68: rf broadcast reads 2-way (free) instead of 4-way at 72
  __shared__ float rowsq[64];
  __shared__ float dtile[64*68];
  const int t = threadIdx.x;
  const int w = t >> 6;
  const int l = t & 63;
  const int bid = blockIdx.x;
  const int b = bid & 7;                 // batch -> XCD (x[b] = 1MB L2-resident)
  const int rest = bid >> 3;
  const int z = rest & 1;                // candidate half
  const int n0 = (rest >> 1) * 64;
  const int cbase = z * 2048;
  const float* xb = x + (size_t)b*FIN*NPTS;

  for (int j=t; j<4096; j+=256){ int row = j & 63, f = j >> 6; rowf[row*68+f] = xb[(size_t)f*NPTS + n0 + row]; }
  if (t < 64) rowsq[t] = sq[b*NPTS + n0 + t];
  __syncthreads();

  const int cl = l & 15;
  const int rl = l >> 4;
  float rsq[4]; int nself[4];
  #pragma unroll
  for (int jr=0;jr<4;++jr){ int r = w*16 + rl*4 + jr; rsq[jr] = rowsq[r]; nself[jr] = n0 + r; }

  float val[16]; int idx[16];
  #pragma unroll
  for (int q=0;q<16;++q){ val[q] = FINF; idx[q] = 0; }
  const int selrow = w*16 + (l>>2);
  const int selc   = l & 3;
  const int selbase = selrow*68 + selc;

  for (int cc=0; cc<2048; cc+=64){
    const int c0 = cbase + cc;
    __syncthreads();                           // xt free to overwrite
    #pragma unroll
    for (int it=0; it<4; ++it){                // stage 64f x 64c, pre-swizzled
      int i4 = it*256 + t;
      int f  = i4 >> 4;
      int c4 = (i4 & 15) << 2;
      float4 v = *(const float4*)(xb + (size_t)f*NPTS + c0 + c4);
      int fp = f ^ c4;
      xt[(c4+0)*64 + fp] = v.x;
      xt[(c4+1)*64 + fp] = v.y;
      xt[(c4+2)*64 + fp] = v.z;
      xt[(c4+3)*64 + fp] = v.w;
    }
    float csq[4];
    #pragma unroll
    for (int jc=0;jc<4;++jc) csq[jc] = sq[b*NPTS + c0 + cl*4 + jc];
    __syncthreads();                           // xt ready

    float acc[4][4];
    #pragma unroll
    for (int jc=0;jc<4;++jc){
      #pragma unroll
      for (int jr=0;jr<4;++jr) acc[jc][jr]=0.f;
    }
    #pragma unroll
    for (int i=0;i<16;++i){                    // logical f4 = 4i; physical = 4(i^cl)
      int fp = ((i ^ cl) << 2);
      float4 xv[4], rf[4];
      #pragma unroll
      for (int jc=0;jc<4;++jc) xv[jc] = *(const float4*)&xt[(cl*4+jc)*64 + fp];
      #pragma unroll
      for (int jr=0;jr<4;++jr) rf[jr] = *(const float4*)&rowf[(w*16+rl*4+jr)*68 + i*4];
      #pragma unroll
      for (int jc=0;jc<4;++jc){
        #pragma unroll
        for (int jr=0;jr<4;++jr){
          acc[jc][jr] = fmaf(xv[jc].x, rf[jr].x, acc[jc][jr]);
          acc[jc][jr] = fmaf(xv[jc].y, rf[jr].y, acc[jc][jr]);
          acc[jc][jr] = fmaf(xv[jc].z, rf[jr].z, acc[jc][jr]);
          acc[jc][jr] = fmaf(xv[jc].w, rf[jr].w, acc[jc][jr]);
        }
      }
    }
    #pragma unroll
    for (int jr=0;jr<4;++jr){                  // d-compute + b128 dtile write
      int c = c0 + cl*4;
      float4 dd;
      dd.x = fmaf(-2.f, acc[0][jr], rsq[jr] + csq[0]); if (c+0 == nself[jr]) dd.x = FINF;
      dd.y = fmaf(-2.f, acc[1][jr], rsq[jr] + csq[1]); if (c+1 == nself[jr]) dd.y = FINF;
      dd.z = fmaf(-2.f, acc[2][jr], rsq[jr] + csq[2]); if (c+2 == nself[jr]) dd.z = FINF;
      dd.w = fmaf(-2.f, acc[3][jr], rsq[jr] + csq[3]); if (c+3 == nself[jr]) dd.w = FINF;
      *(float4*)&dtile[(w*16 + rl*4 + jr)*68 + cl*4] = dd;
    }
    // two-phase selection: survivor mask (cheap) then insertion only for survivors
    {
      float thr = val[15];
      unsigned mask = 0;
      #pragma unroll
      for (int j=15;j>=0;--j){
        float d = dtile[selbase + 4*j];
        mask = (mask << 1) | (d < thr ? 1u : 0u);
      }
      while (mask){
        int j = __builtin_ctz(mask);
        mask &= mask - 1;
        float d = dtile[selbase + 4*j];        // re-read from LDS (no dynamic reg array)
        if (d < val[15]){
          val[15] = d; idx[15] = c0 + selc + 4*j;
          #pragma unroll
          for (int q=15;q>0;--q){
            bool s_ = val[q] < val[q-1];
            float tv = val[q], tu = val[q-1];
            val[q]   = s_ ? tu : tv;
            val[q-1] = s_ ? tv : tu;
            int iv = idx[q], iu = idx[q-1];
            idx[q]   = s_ ? iu : iv;
            idx[q-1] = s_ ? iv : iu;
          }
        }
      }
    }
  }

  // merge 4 sorted per-lane lists -> sorted global top-16 of this half
  float myv[4]; int myi[4];
  #pragma unroll
  for (int round=0; round<16; ++round){
    float v = val[0]; int ii = idx[0]; int src = selc;
    #pragma unroll
    for (int mm=1; mm<4; mm<<=1){
      float ov = __shfl_xor(v, mm);
      int   oi = __shfl_xor(ii, mm);
      int   os = __shfl_xor(src, mm);
      bool take = (ov < v) || (ov == v && os < src);
      v = take ? ov : v; ii = take ? oi : ii; src = take ? os : src;
    }
    if (selc == src){
      #pragma unroll
      for (int q=0;q<15;++q){ val[q]=val[q+1]; idx[q]=idx[q+1]; }
      val[15] = FINF;
    }
    if ((round & 3) == selc){ myv[round>>2] = v; myi[round>>2] = ii; }
  }
  {
    int bn = b*NPTS + n0 + selrow;
    float2* pp = pairs + (size_t)bn*32 + z*16;
    #pragma unroll
    for (int q=0;q<4;++q) pp[q*4 + selc] = make_float2(myv[q], __int_as_float(myi[q]));
  }
}

// ---------------- merge two sorted 16-lists per row -> final 16 neighbor indices ----------------
__global__ __launch_bounds__(256) void kmerge_kernel(const float2* __restrict__ pairs, int* __restrict__ idxout){
  int bn = blockIdx.x*256 + threadIdx.x;
  const float2* p = pairs + (size_t)bn*32;
  float val[16]; int idx[16];
  #pragma unroll
  for (int q=0;q<16;++q){ float2 e = p[q]; val[q] = e.x; idx[q] = __float_as_int(e.y); }  // z=0 sorted
  #pragma unroll
  for (int j=16;j<32;++j){
    float2 e = p[j];
    if (e.x < val[15]){
      val[15] = e.x; idx[15] = __float_as_int(e.y);
      #pragma unroll
      for (int q=15;q>0;--q){
        bool s_ = val[q] < val[q-1];
        float tv = val[q], tu = val[q-1];
        val[q] = s_?tu:tv; val[q-1] = s_?tv:tu;
        int iv = idx[q], iu = idx[q-1];
        idx[q] = s_?iu:iv; idx[q-1] = s_?iv:iu;
      }
    }
  }
  int* op = idxout + (size_t)bn*KNB;
  #pragma unroll
  for (int q=0;q<KNB;++q) op[q] = idx[q];
}

// ---------------- gather V at neighbors: sel=Ubar+(gamma>=0?max:min), channel stats ----------------
// 256 thr: o = t&127, h = t>>7 picks point half; each thread owns all 16 neighbors of its points.
__global__ __launch_bounds__(256) void gather_kernel(const float* __restrict__ vt, const float* __restrict__ ubar,
                                                     const int* __restrict__ idxnb, const float* __restrict__ gamma,
                                                     float* __restrict__ outsel, float* __restrict__ gsum,
                                                     float* __restrict__ gsumsq){
  __shared__ float red[2*FOUT];
  const int t = threadIdx.x;
  const int o = t & 127;
  const int h = __builtin_amdgcn_readfirstlane(t >> 7);   // wave-uniform -> idx via s_load
  const int bid = blockIdx.x;
  const int b = bid & 7;                                  // batch -> XCD: vt[b]=2MB L2-resident
  const int grp = bid >> 3;
  const int nb = grp*64 + h*32;
  const float gam = gamma[o];
  const float* vtb = vt + (size_t)b*NPTS*FOUT;
  float bs = 0.f, bsq = 0.f;
  for (int p=0; p<32; ++p){
    const int n = nb + p;
    const int bn = b*NPTS + n;
    const int* ip = idxnb + (size_t)bn*KNB;
    float mx = -FINF, mn = FINF, s1 = 0.f, s2 = 0.f;
    #pragma unroll
    for (int kk=0; kk<KNB; ++kk){
      int m = ip[kk];
      float v = vtb[(size_t)m*FOUT + o];                  // 256B coalesced per neighbor
      mx = fmaxf(mx, v); mn = fminf(mn, v); s1 += v; s2 = fmaf(v, v, s2);
    }
    float c = ubar[(size_t)bn*FOUT + o];
    outsel[((size_t)b*FOUT + o)*NPTS + n] = c + (gam >= 0.f ? mx : mn);
    bs  += fmaf(16.f, c, s1);                             // sum_k y = 16c + S1
    bsq += fmaf(16.f*c, c, fmaf(2.f*c, s1, s2));          // sum_k y^2 = 16c^2 + 2c S1 + S2
  }
  if (h == 1){ red[o] = bs; red[FOUT+o] = bsq; }
  __syncthreads();
  if (h == 0){ atomicAdd(&gsum[o], bs + red[o]); atomicAdd(&gsumsq[o], bsq + red[FOUT+o]); }
}

// ---------------- BN stats -> per-channel affine a,c ----------------
__global__ void stats_kernel(const float* __restrict__ gsum, const float* __restrict__ gsumsq,
                             const float* __restrict__ gamma, const float* __restrict__ beta,
                             float* __restrict__ ac){
  int o = threadIdx.x;
  const float invM = 1.f / (float)(BATCH*NPTS*KNB);
  float mean = gsum[o] * invM;
  float var  = gsumsq[o] * invM - mean*mean;
  float r = rsqrtf(var + BN_EPS);
  float a = gamma[o] * r;
  ac[o] = a;
  ac[FOUT+o] = beta[o] - mean * a;
}

// ---------------- in-place relu(a*y+c) on d_out ----------------
__global__ __launch_bounds__(256) void apply_kernel(float* __restrict__ out, const float* __restrict__ ac){
  int i4 = blockIdx.x*256 + threadIdx.x;
  int o = (i4 >> 10) & 127;
  float a = ac[o], c = ac[FOUT+o];
  float4* p = (float4*)out;
  float4 v = p[i4];
  v.x = fmaxf(fmaf(a, v.x, c), 0.f);
  v.y = fmaxf(fmaf(a, v.y, c), 0.f);
  v.z = fmaxf(fmaf(a, v.z, c), 0.f);
  v.w = fmaxf(fmaf(a, v.w, c), 0.f);
  p[i4] = v;
}

extern "C" void kernel_launch(void* const* d_in, const int* in_sizes, int n_in,
                              void* d_out, int out_size, void* d_ws, size_t ws_size,
                              hipStream_t stream){
  const float* x     = (const float*)d_in[0];
  const float* W     = (const float*)d_in[1];
  const float* bias  = (const float*)d_in[2];
  const float* gamma = (const float*)d_in[3];
  const float* beta  = (const float*)d_in[4];
  char* ws = (char*)d_ws;
  float*  sq     = (float*)(ws + OFF_SQ);
  int*    idxnb  = (int*)(ws + OFF_IDX);
  float2* pairs  = (float2*)(ws + OFF_PAIRS);
  float*  ubar   = (float*)(ws + OFF_UBAR);
  float*  vt     = (float*)(ws + OFF_VT);
  float*  gsum   = (float*)(ws + OFF_GSUM);
  float*  gsumsq = (float*)(ws + OFF_GSUMSQ);
  float*  ac     = (float*)(ws + OFF_AC);
  float*  out    = (float*)d_out;

  hipMemsetAsync(ws + OFF_GSUM, 0, 2*FOUT*4, stream);
  sq_kernel    <<<BATCH*NPTS/256, 256, 0, stream>>>(x, sq);
  uv_kernel    <<<BATCH*NPTS/64,  256, 0, stream>>>(x, W, bias, ubar, vt);
  knn_kernel   <<<BATCH*(NPTS/64)*2, 256, 0, stream>>>(x, sq, pairs);
  kmerge_kernel<<<BATCH*NPTS/256, 256, 0, stream>>>(pairs, idxnb);
  gather_kernel<<<BATCH*(NPTS/64), 256, 0, stream>>>(vt, ubar, idxnb, gamma, out, gsum, gsumsq);
  stats_kernel <<<1, FOUT, 0, stream>>>(gsum, gsumsq, gamma, beta, ac);
  apply_kernel <<<BATCH*FOUT*NPTS/1024, 256, 0, stream>>>(out, ac);
}